// Round 8
// baseline (1829.640 us; speedup 1.0000x reference)
//
#include <hip/hip_runtime.h>
#include <hip/hip_bf16.h>

#define MDIM 4096
#define KDIM 4096
#define NDIM 11008

#define BM 256
#define BN 256
#define BK 64             // int8 elements per K-tile (one K=64 MFMA slice)
#define NT (KDIM / BK)    // 64 K-tiles

typedef int v4i __attribute__((ext_vector_type(4)));

__device__ __forceinline__ void gload_lds16(const void* g, void* s) {
  __builtin_amdgcn_global_load_lds(
      (const __attribute__((address_space(1))) void*)g,
      (__attribute__((address_space(3))) void*)s, 16, 0, 0);
}

// ---------------------------------------------------------------------------
// Kernel 1: per-token dynamic int8 quant of f32 x -> q[M,K] int8, scale[M] f32
// ---------------------------------------------------------------------------
__global__ __launch_bounds__(256) void quant_kernel(
    const float* __restrict__ x,
    unsigned* __restrict__ q,
    float* __restrict__ scales)
{
  const int row = blockIdx.x;
  const int tid = threadIdx.x;
  const float4* xr = (const float4*)(x + (size_t)row * KDIM);
  float4 v[4];
#pragma unroll
  for (int i = 0; i < 4; ++i) v[i] = xr[tid + i * 256];

  float amax = 0.f;
#pragma unroll
  for (int i = 0; i < 4; ++i) {
    amax = fmaxf(amax, fmaxf(fmaxf(fabsf(v[i].x), fabsf(v[i].y)),
                             fmaxf(fabsf(v[i].z), fabsf(v[i].w))));
  }
#pragma unroll
  for (int off = 32; off >= 1; off >>= 1)
    amax = fmaxf(amax, __shfl_xor(amax, off));
  __shared__ float red[4];
  const int lane = tid & 63, wv = tid >> 6;
  if (lane == 0) red[wv] = amax;
  __syncthreads();
  amax = fmaxf(fmaxf(red[0], red[1]), fmaxf(red[2], red[3]));

  const float scale = fmaxf(amax, 1e-7f) * (1.0f / 127.0f);
  const float rs = 1.0f / scale;
  if (tid == 0) scales[row] = scale;

#pragma unroll
  for (int i = 0; i < 4; ++i) {
    float e[4] = {v[i].x, v[i].y, v[i].z, v[i].w};
    unsigned w = 0;
#pragma unroll
    for (int j = 0; j < 4; ++j) {
      float qf = rintf(e[j] * rs);
      qf = fminf(fmaxf(qf, -128.f), 127.f);
      int qi = (int)qf;
      w |= ((unsigned)(qi & 255)) << (8 * j);
    }
    q[(size_t)row * (KDIM / 4) + tid + i * 256] = w;
  }
}

// ---------------------------------------------------------------------------
// Kernel 2: pack int32 weight [N,K] -> int8 [N,K]
// ---------------------------------------------------------------------------
__global__ __launch_bounds__(256) void pack_kernel(
    const int4* __restrict__ w32, unsigned* __restrict__ w8, int n_units)
{
  int idx = blockIdx.x * 256 + threadIdx.x;
  const int stride = gridDim.x * 256;
  for (; idx < n_units; idx += stride) {
    int4 v = w32[idx];
    unsigned d = ((unsigned)(v.x & 255)) | ((unsigned)(v.y & 255) << 8) |
                 ((unsigned)(v.z & 255) << 16) | ((unsigned)(v.w & 255) << 24);
    w8[idx] = d;
  }
}

// ---------------------------------------------------------------------------
// Kernel 3: int8 GEMM, 256x256 tile, BK=64, 2-phase/tile, 64 KiB LDS ->
// 2 blocks/CU (m114 cross-block overlap: one block's MFMA region hides the
// other's memory region). 512 threads = 8 waves (2M x 4N), per-wave 128x64.
// Swizzle: chunk c ^= ((r>>1)&3) both-sides (conflict-free, verified r6).
// ---------------------------------------------------------------------------
__global__ __launch_bounds__(512, 4) void gemm_i8_kernel(
    const signed char* __restrict__ qa,   // [M,K] int8
    const signed char* __restrict__ wb,   // [N,K] int8
    const float* __restrict__ scales,     // [M]
    const float* __restrict__ wscale,     // [N]
    const float* __restrict__ bias,       // [N]
    float* __restrict__ out)              // [M,N] f32
{
  __shared__ __align__(16) signed char As[2][256 * 64];  // 32 KiB
  __shared__ __align__(16) signed char Bs[2][256 * 64];  // 32 KiB

  const int tid = threadIdx.x;
  const int lane = tid & 63;
  const int wv = tid >> 6;       // 0..7
  const int wr = wv >> 2;        // 0..1 (M half)
  const int wc = wv & 3;         // 0..3 (N quarter)

  const int n0 = blockIdx.x * BN;
  const int m0 = blockIdx.y * BM;

  const signed char* Ag = qa + (size_t)m0 * KDIM;
  const signed char* Bg = wb + (size_t)n0 * KDIM;

  // stage one 16 KiB tile (256 rows x 64 B) for K-tile kt. LDS dest linear
  // (wave-uniform base + lane*16); swizzle via permuted GLOBAL source chunk:
  // c_g = c_lds ^ ((r>>1)&3). 2 gload_lds per thread.
  auto stageT = [&](signed char* dst, const signed char* g, int kt) {
#pragma unroll
    for (int i = 0; i < 2; ++i) {
      const int chunk = i * 512 + tid;              // 0..1023
      const int r = chunk >> 2;                     // row 0..255
      const int cg = (chunk & 3) ^ ((r >> 1) & 3);  // swizzled global chunk
      gload_lds16(g + (size_t)r * KDIM + (size_t)kt * BK + cg * 16,
                  dst + (i * 512 + wv * 64) * 16);
    }
  };

  // fragment reads: global chunk ksel of row r lives at LDS chunk
  // ksel ^ ((r>>1)&3); frag-row bases are multiples of 16 so the XOR term
  // is a per-lane constant.
  const int swz16 = (((lane >> 4) ^ (((lane & 15) >> 1) & 3)) << 4);
  const int frow_a = wr * 128 + (lane & 15);
  const int frow_b = wc * 64 + (lane & 15);

  auto ardA = [&](const signed char* plane, int mi) -> v4i {
    return *(const v4i*)(plane + (frow_a + mi * 16) * 64 + swz16);
  };
  auto ardB = [&](const signed char* plane, int ni) -> v4i {
    return *(const v4i*)(plane + (frow_b + ni * 16) * 64 + swz16);
  };

  v4i acc[8][4] = {};
  v4i bfrag[4];

  // prologue: stage tile 0 (A+B, 4 loads/thread)
  stageT(&As[0][0], Ag, 0);
  stageT(&Bs[0][0], Bg, 0);
  asm volatile("s_waitcnt vmcnt(0)" ::: "memory");
  __builtin_amdgcn_s_barrier();

  for (int t = 0; t < NT; ++t) {
    const int cur = t & 1;
    const int nxt = cur ^ 1;
    const signed char* Ac = &As[cur][0];
    const signed char* Bc = &Bs[cur][0];
    v4i af[4];

    // ---------- phase 1: acc rows 0-3 ----------
#pragma unroll
    for (int mi = 0; mi < 4; ++mi) af[mi] = ardA(Ac, mi);
#pragma unroll
    for (int ni = 0; ni < 4; ++ni) bfrag[ni] = ardB(Bc, ni);
    if (t + 1 < NT) stageT(&As[nxt][0], Ag, t + 1);
    __builtin_amdgcn_s_barrier();
    asm volatile("s_waitcnt lgkmcnt(0)" ::: "memory");
    __builtin_amdgcn_s_setprio(1);
#pragma unroll
    for (int mi = 0; mi < 4; ++mi)
#pragma unroll
      for (int ni = 0; ni < 4; ++ni)
        acc[mi][ni] = __builtin_amdgcn_mfma_i32_16x16x64_i8(
            af[mi], bfrag[ni], acc[mi][ni], 0, 0, 0);
    __builtin_amdgcn_s_setprio(0);
    __builtin_amdgcn_s_barrier();

    // ---------- phase 2: acc rows 4-7 (reuse bfrag) ----------
#pragma unroll
    for (int mi = 0; mi < 4; ++mi) af[mi] = ardA(Ac, mi + 4);
    if (t + 1 < NT) stageT(&Bs[nxt][0], Bg, t + 1);
    __builtin_amdgcn_s_barrier();
    asm volatile("s_waitcnt lgkmcnt(0)" ::: "memory");
    __builtin_amdgcn_s_setprio(1);
#pragma unroll
    for (int mi = 0; mi < 4; ++mi)
#pragma unroll
      for (int ni = 0; ni < 4; ++ni)
        acc[mi + 4][ni] = __builtin_amdgcn_mfma_i32_16x16x64_i8(
            af[mi], bfrag[ni], acc[mi + 4][ni], 0, 0, 0);
    __builtin_amdgcn_s_setprio(0);
    // next tile must be fully resident before ph1(t+1); per-wave drain of its
    // own 4 staged loads + barrier makes it collective.
    asm volatile("s_waitcnt vmcnt(0)" ::: "memory");
    __builtin_amdgcn_s_barrier();
  }

  // epilogue: dequant + bias, f32 store
  const int cl = lane & 15;
  const int rb = (lane >> 4) * 4;
#pragma unroll
  for (int ni = 0; ni < 4; ++ni) {
    const int n = n0 + wc * 64 + ni * 16 + cl;
    const float wsc = wscale[n];
    const float bs = bias[n];
#pragma unroll
    for (int mi = 0; mi < 8; ++mi) {
      const int mb = m0 + wr * 128 + mi * 16 + rb;
#pragma unroll
      for (int j = 0; j < 4; ++j) {
        const int m = mb + j;
        out[(size_t)m * NDIM + n] =
            (float)acc[mi][ni][j] * scales[m] * wsc + bs;
      }
    }
  }
}

// ---------------------------------------------------------------------------
extern "C" void kernel_launch(void* const* d_in, const int* in_sizes, int n_in,
                              void* d_out, int out_size, void* d_ws, size_t ws_size,
                              hipStream_t stream) {
  const float* x = (const float*)d_in[0];        // f32 [M,K] (fp16 upcast)
  const int* w32 = (const int*)d_in[1];          // int32 [N,K]
  const float* wscale = (const float*)d_in[2];   // [N]
  const float* bias = (const float*)d_in[3];     // [N]
  float* out = (float*)d_out;                    // f32 [M,N]

  float* scales = (float*)d_ws;                                  // 16 KB slot
  signed char* qbuf = (signed char*)d_ws + 16384;                // M*K int8
  signed char* wpack = (signed char*)d_ws + 16384 + (size_t)MDIM * KDIM;

  quant_kernel<<<MDIM, 256, 0, stream>>>(x, (unsigned*)qbuf, scales);

  const int n_units = (NDIM * KDIM) / 4;
  pack_kernel<<<2048, 256, 0, stream>>>((const int4*)w32, (unsigned*)wpack,
                                        n_units);

  dim3 grid(NDIM / BN, MDIM / BM);   // 43 x 16
  gemm_i8_kernel<<<grid, 512, 0, stream>>>(qbuf, wpack, scales, wscale, bias,
                                           out);
}

// Round 9
// 328.264 us; speedup vs baseline: 5.5737x; 5.5737x over previous
//
#include <hip/hip_runtime.h>
#include <hip/hip_bf16.h>

#define MDIM 4096
#define KDIM 4096
#define NDIM 11008

#define BM 256
#define BN 256
#define BK 128            // int8 elements per K-tile (two K=64 MFMA slices)
#define NT (KDIM / BK)    // 32 K-tiles

#define NBX (NDIM / BN)   // 43
#define NBY (MDIM / BM)   // 16
#define NWG (NBX * NBY)   // 688 = 8 * 86

typedef int v4i __attribute__((ext_vector_type(4)));

__device__ __forceinline__ void gload_lds16(const void* g, void* s) {
  __builtin_amdgcn_global_load_lds(
      (const __attribute__((address_space(1))) void*)g,
      (__attribute__((address_space(3))) void*)s, 16, 0, 0);
}

// ---------------------------------------------------------------------------
// Kernel 1: per-token dynamic int8 quant of f32 x -> q[M,K] int8, scale[M] f32
// ---------------------------------------------------------------------------
__global__ __launch_bounds__(256) void quant_kernel(
    const float* __restrict__ x,
    unsigned* __restrict__ q,
    float* __restrict__ scales)
{
  const int row = blockIdx.x;
  const int tid = threadIdx.x;
  const float4* xr = (const float4*)(x + (size_t)row * KDIM);
  float4 v[4];
#pragma unroll
  for (int i = 0; i < 4; ++i) v[i] = xr[tid + i * 256];

  float amax = 0.f;
#pragma unroll
  for (int i = 0; i < 4; ++i) {
    amax = fmaxf(amax, fmaxf(fmaxf(fabsf(v[i].x), fabsf(v[i].y)),
                             fmaxf(fabsf(v[i].z), fabsf(v[i].w))));
  }
#pragma unroll
  for (int off = 32; off >= 1; off >>= 1)
    amax = fmaxf(amax, __shfl_xor(amax, off));
  __shared__ float red[4];
  const int lane = tid & 63, wv = tid >> 6;
  if (lane == 0) red[wv] = amax;
  __syncthreads();
  amax = fmaxf(fmaxf(red[0], red[1]), fmaxf(red[2], red[3]));

  const float scale = fmaxf(amax, 1e-7f) * (1.0f / 127.0f);
  const float rs = 1.0f / scale;
  if (tid == 0) scales[row] = scale;

#pragma unroll
  for (int i = 0; i < 4; ++i) {
    float e[4] = {v[i].x, v[i].y, v[i].z, v[i].w};
    unsigned w = 0;
#pragma unroll
    for (int j = 0; j < 4; ++j) {
      float qf = rintf(e[j] * rs);
      qf = fminf(fmaxf(qf, -128.f), 127.f);
      int qi = (int)qf;
      w |= ((unsigned)(qi & 255)) << (8 * j);
    }
    q[(size_t)row * (KDIM / 4) + tid + i * 256] = w;
  }
}

// ---------------------------------------------------------------------------
// Kernel 2: pack int32 weight [N,K] -> int8 [N,K]
// ---------------------------------------------------------------------------
__global__ __launch_bounds__(256) void pack_kernel(
    const int4* __restrict__ w32, unsigned* __restrict__ w8, int n_units)
{
  int idx = blockIdx.x * 256 + threadIdx.x;
  const int stride = gridDim.x * 256;
  for (; idx < n_units; idx += stride) {
    int4 v = w32[idx];
    unsigned d = ((unsigned)(v.x & 255)) | ((unsigned)(v.y & 255) << 8) |
                 ((unsigned)(v.z & 255) << 16) | ((unsigned)(v.w & 255) << 24);
    w8[idx] = d;
  }
}

// ---------------------------------------------------------------------------
// Kernel 3: int8 GEMM, 256x256 tile, 8-phase schedule, deep prefetch
// (r7 structure, unchanged). NEW: 1-D grid with XCD-chunked, column-major
// (M-fastest) block mapping — A (16.8 MB) becomes the L3-resident operand,
// weight (45 MB) streams exactly once; each XCD's active B-panels stay in
// its private L2 with 16-way reuse.
// ---------------------------------------------------------------------------
__global__ __launch_bounds__(512, 2) void gemm_i8_kernel(
    const signed char* __restrict__ qa,   // [M,K] int8
    const signed char* __restrict__ wb,   // [N,K] int8
    const float* __restrict__ scales,     // [M]
    const float* __restrict__ wscale,     // [N]
    const float* __restrict__ bias,       // [N]
    float* __restrict__ out)              // [M,N] f32
{
  __shared__ __align__(16) signed char As[2][2][256 * 64];  // 64 KiB
  __shared__ __align__(16) signed char Bs[2][2][256 * 64];  // 64 KiB

  const int tid = threadIdx.x;
  const int lane = tid & 63;
  const int wv = tid >> 6;       // 0..7
  const int wr = wv >> 2;        // 0..1 (M half)
  const int wc = wv & 3;         // 0..3 (N quarter)

  // XCD-chunked (688 = 8*86, bijective) + column-major (by fastest)
  const int id = blockIdx.x;
  const int lin = (id & 7) * (NWG / 8) + (id >> 3);
  const int bx = lin / NBY;      // N-tile 0..42 (slow)
  const int by = lin % NBY;      // M-tile 0..15 (fast)
  const int n0 = bx * BN;
  const int m0 = by * BM;

  const signed char* Ag = qa + (size_t)m0 * KDIM;
  const signed char* Bg = wb + (size_t)n0 * KDIM;

  // stage one 16 KiB half-tile (256 rows x 64 B of K-half kh) for tile kt.
  // LDS dest linear (wave-uniform base + lane*16); swizzle via permuted
  // GLOBAL source chunk: c_g = c_lds ^ ((r>>1)&3).  2 loads per thread.
  auto stageH = [&](signed char* dst, const signed char* g, int kt, int kh) {
#pragma unroll
    for (int i = 0; i < 2; ++i) {
      const int chunk = i * 512 + tid;              // 0..1023
      const int r = chunk >> 2;                     // row 0..255
      const int cg = (chunk & 3) ^ ((r >> 1) & 3);  // swizzled global chunk
      gload_lds16(g + (size_t)r * KDIM + (size_t)kt * BK + kh * 64 + cg * 16,
                  dst + (i * 512 + wv * 64) * 16);
    }
  };

  // fragment reads: global chunk ksel of row r lives at LDS chunk
  // ksel ^ ((r>>1)&3); frag-row bases are multiples of 16 so the XOR term
  // is a per-lane constant.
  const int swz16 = (((lane >> 4) ^ (((lane & 15) >> 1) & 3)) << 4);
  const int frow_a = wr * 128 + (lane & 15);
  const int frow_b = wc * 64 + (lane & 15);

  auto ardA = [&](const signed char* plane, int mi) -> v4i {
    return *(const v4i*)(plane + (frow_a + mi * 16) * 64 + swz16);
  };
  auto ardB = [&](const signed char* plane, int ni) -> v4i {
    return *(const v4i*)(plane + (frow_b + ni * 16) * 64 + swz16);
  };

  v4i acc[8][4] = {};
  v4i bfrag[4];

  // prologue: stage kh0(0), kh1(0), kh0(1)  (12 loads/thread)
  stageH(&As[0][0][0], Ag, 0, 0);
  stageH(&Bs[0][0][0], Bg, 0, 0);
  stageH(&As[0][1][0], Ag, 0, 1);
  stageH(&Bs[0][1][0], Bg, 0, 1);
  stageH(&As[1][0][0], Ag, 1, 0);
  stageH(&Bs[1][0][0], Bg, 1, 0);
  asm volatile("s_waitcnt vmcnt(8)" ::: "memory");  // kh0(0) resident
  __builtin_amdgcn_s_barrier();

  for (int t = 0; t < NT; ++t) {
    const int cur = t & 1;
    const int nxt = cur ^ 1;
    const signed char* A0 = &As[cur][0][0];
    const signed char* A1 = &As[cur][1][0];
    const signed char* B0 = &Bs[cur][0][0];
    const signed char* B1 = &Bs[cur][1][0];
    v4i af[4];

    // ---------- phase 1: kk0, acc rows 0-3 ----------
#pragma unroll
    for (int mi = 0; mi < 4; ++mi) af[mi] = ardA(A0, mi);
#pragma unroll
    for (int ni = 0; ni < 4; ++ni) bfrag[ni] = ardB(B0, ni);
    if (t + 1 < NT) stageH(&As[nxt][1][0], Ag, t + 1, 1);
    __builtin_amdgcn_s_barrier();
    asm volatile("s_waitcnt lgkmcnt(0)" ::: "memory");
    __builtin_amdgcn_s_setprio(1);
#pragma unroll
    for (int mi = 0; mi < 4; ++mi)
#pragma unroll
      for (int ni = 0; ni < 4; ++ni)
        acc[mi][ni] = __builtin_amdgcn_mfma_i32_16x16x64_i8(
            af[mi], bfrag[ni], acc[mi][ni], 0, 0, 0);
    __builtin_amdgcn_s_setprio(0);
    __builtin_amdgcn_s_barrier();

    // ---------- phase 2: kk0, acc rows 4-7 ----------
#pragma unroll
    for (int mi = 0; mi < 4; ++mi) af[mi] = ardA(A0, mi + 4);
    if (t + 1 < NT) stageH(&Bs[nxt][1][0], Bg, t + 1, 1);
    __builtin_amdgcn_s_barrier();
    asm volatile("s_waitcnt lgkmcnt(0)" ::: "memory");
    __builtin_amdgcn_s_setprio(1);
#pragma unroll
    for (int mi = 0; mi < 4; ++mi)
#pragma unroll
      for (int ni = 0; ni < 4; ++ni)
        acc[mi + 4][ni] = __builtin_amdgcn_mfma_i32_16x16x64_i8(
            af[mi], bfrag[ni], acc[mi + 4][ni], 0, 0, 0);
    __builtin_amdgcn_s_setprio(0);
    // publish kh1(t) (staged during tile t-1 ph1/ph2); keep 8 in flight
    if (t + 1 < NT) { asm volatile("s_waitcnt vmcnt(8)" ::: "memory"); }
    else            { asm volatile("s_waitcnt vmcnt(0)" ::: "memory"); }
    __builtin_amdgcn_s_barrier();

    // ---------- phase 3: kk1, acc rows 0-3 ----------
#pragma unroll
    for (int mi = 0; mi < 4; ++mi) af[mi] = ardA(A1, mi);
#pragma unroll
    for (int ni = 0; ni < 4; ++ni) bfrag[ni] = ardB(B1, ni);
    if (t + 2 < NT) stageH(&As[cur][0][0], Ag, t + 2, 0);
    __builtin_amdgcn_s_barrier();
    asm volatile("s_waitcnt lgkmcnt(0)" ::: "memory");
    __builtin_amdgcn_s_setprio(1);
#pragma unroll
    for (int mi = 0; mi < 4; ++mi)
#pragma unroll
      for (int ni = 0; ni < 4; ++ni)
        acc[mi][ni] = __builtin_amdgcn_mfma_i32_16x16x64_i8(
            af[mi], bfrag[ni], acc[mi][ni], 0, 0, 0);
    __builtin_amdgcn_s_setprio(0);
    __builtin_amdgcn_s_barrier();

    // ---------- phase 4: kk1, acc rows 4-7 ----------
#pragma unroll
    for (int mi = 0; mi < 4; ++mi) af[mi] = ardA(A1, mi + 4);
    if (t + 2 < NT) stageH(&Bs[cur][0][0], Bg, t + 2, 0);
    __builtin_amdgcn_s_barrier();
    asm volatile("s_waitcnt lgkmcnt(0)" ::: "memory");
    __builtin_amdgcn_s_setprio(1);
#pragma unroll
    for (int mi = 0; mi < 4; ++mi)
#pragma unroll
      for (int ni = 0; ni < 4; ++ni)
        acc[mi + 4][ni] = __builtin_amdgcn_mfma_i32_16x16x64_i8(
            af[mi], bfrag[ni], acc[mi + 4][ni], 0, 0, 0);
    __builtin_amdgcn_s_setprio(0);
    // publish kh0(t+1) (staged during tile t-1 ph3/ph4)
    if (t + 2 < NT)      { asm volatile("s_waitcnt vmcnt(8)" ::: "memory"); }
    else if (t + 1 < NT) { asm volatile("s_waitcnt vmcnt(4)" ::: "memory"); }
    __builtin_amdgcn_s_barrier();
  }

  // epilogue: dequant + bias, f32 store
  const int cl = lane & 15;
  const int rb = (lane >> 4) * 4;
#pragma unroll
  for (int ni = 0; ni < 4; ++ni) {
    const int n = n0 + wc * 64 + ni * 16 + cl;
    const float wsc = wscale[n];
    const float bs = bias[n];
#pragma unroll
    for (int mi = 0; mi < 8; ++mi) {
      const int mb = m0 + wr * 128 + mi * 16 + rb;
#pragma unroll
      for (int j = 0; j < 4; ++j) {
        const int m = mb + j;
        out[(size_t)m * NDIM + n] =
            (float)acc[mi][ni][j] * scales[m] * wsc + bs;
      }
    }
  }
}

// ---------------------------------------------------------------------------
extern "C" void kernel_launch(void* const* d_in, const int* in_sizes, int n_in,
                              void* d_out, int out_size, void* d_ws, size_t ws_size,
                              hipStream_t stream) {
  const float* x = (const float*)d_in[0];        // f32 [M,K] (fp16 upcast)
  const int* w32 = (const int*)d_in[1];          // int32 [N,K]
  const float* wscale = (const float*)d_in[2];   // [N]
  const float* bias = (const float*)d_in[3];     // [N]
  float* out = (float*)d_out;                    // f32 [M,N]

  float* scales = (float*)d_ws;                                  // 16 KB slot
  signed char* qbuf = (signed char*)d_ws + 16384;                // M*K int8
  signed char* wpack = (signed char*)d_ws + 16384 + (size_t)MDIM * KDIM;

  quant_kernel<<<MDIM, 256, 0, stream>>>(x, (unsigned*)qbuf, scales);

  const int n_units = (NDIM * KDIM) / 4;
  pack_kernel<<<2048, 256, 0, stream>>>((const int4*)w32, (unsigned*)wpack,
                                        n_units);

  gemm_i8_kernel<<<NWG, 512, 0, stream>>>(qbuf, wpack, scales, wscale, bias,
                                          out);
}

// Round 10
// 308.640 us; speedup vs baseline: 5.9281x; 1.0636x over previous
//
#include <hip/hip_runtime.h>
#include <hip/hip_bf16.h>

#define MDIM 4096
#define KDIM 4096
#define NDIM 11008

#define BM 256
#define BN 256
#define BK 128            // int8 elements per K-tile (two K=64 MFMA slices)
#define NT (KDIM / BK)    // 32 K-tiles

typedef int v4i __attribute__((ext_vector_type(4)));

__device__ __forceinline__ void gload_lds16(const void* g, void* s) {
  __builtin_amdgcn_global_load_lds(
      (const __attribute__((address_space(1))) void*)g,
      (__attribute__((address_space(3))) void*)s, 16, 0, 0);
}

// ---------------------------------------------------------------------------
// Kernel 1: per-token dynamic int8 quant of f32 x -> q[M,K] int8, scale[M] f32
// ---------------------------------------------------------------------------
__global__ __launch_bounds__(256) void quant_kernel(
    const float* __restrict__ x,
    unsigned* __restrict__ q,
    float* __restrict__ scales)
{
  const int row = blockIdx.x;
  const int tid = threadIdx.x;
  const float4* xr = (const float4*)(x + (size_t)row * KDIM);
  float4 v[4];
#pragma unroll
  for (int i = 0; i < 4; ++i) v[i] = xr[tid + i * 256];

  float amax = 0.f;
#pragma unroll
  for (int i = 0; i < 4; ++i) {
    amax = fmaxf(amax, fmaxf(fmaxf(fabsf(v[i].x), fabsf(v[i].y)),
                             fmaxf(fabsf(v[i].z), fabsf(v[i].w))));
  }
#pragma unroll
  for (int off = 32; off >= 1; off >>= 1)
    amax = fmaxf(amax, __shfl_xor(amax, off));
  __shared__ float red[4];
  const int lane = tid & 63, wv = tid >> 6;
  if (lane == 0) red[wv] = amax;
  __syncthreads();
  amax = fmaxf(fmaxf(red[0], red[1]), fmaxf(red[2], red[3]));

  const float scale = fmaxf(amax, 1e-7f) * (1.0f / 127.0f);
  const float rs = 1.0f / scale;
  if (tid == 0) scales[row] = scale;

#pragma unroll
  for (int i = 0; i < 4; ++i) {
    float e[4] = {v[i].x, v[i].y, v[i].z, v[i].w};
    unsigned w = 0;
#pragma unroll
    for (int j = 0; j < 4; ++j) {
      float qf = rintf(e[j] * rs);
      qf = fminf(fmaxf(qf, -128.f), 127.f);
      int qi = (int)qf;
      w |= ((unsigned)(qi & 255)) << (8 * j);
    }
    q[(size_t)row * (KDIM / 4) + tid + i * 256] = w;
  }
}

// ---------------------------------------------------------------------------
// Kernel 2: pack int32 weight [N,K] -> int8 [N,K]
// ---------------------------------------------------------------------------
__global__ __launch_bounds__(256) void pack_kernel(
    const int4* __restrict__ w32, unsigned* __restrict__ w8, int n_units)
{
  int idx = blockIdx.x * 256 + threadIdx.x;
  const int stride = gridDim.x * 256;
  for (; idx < n_units; idx += stride) {
    int4 v = w32[idx];
    unsigned d = ((unsigned)(v.x & 255)) | ((unsigned)(v.y & 255) << 8) |
                 ((unsigned)(v.z & 255) << 16) | ((unsigned)(v.w & 255) << 24);
    w8[idx] = d;
  }
}

// ---------------------------------------------------------------------------
// Kernel 3: int8 GEMM, 256x256 tile, 2-PHASE per K-tile (4 barriers/tile).
// Per phase: 8 pre-barrier ds_reads (A quad-0 + B), 2 half-tile stages,
// barrier, lgkm(0), setprio, 16 MFMA, 4 unfenced ds_reads (A quad-1,
// compiler-scheduled under the MFMAs), 16 MFMA, setprio, counted vmcnt,
// barrier. Deep vmcnt FIFO (8-12 outstanding, drain 4/phase, never 0 in
// steady state). Swizzle: chunk c ^= ((r>>1)&3) both-sides (conflict-free,
// verified r6). Plain 2-D grid (row-major; XCD remap reverted — r9 cost 5%).
// ---------------------------------------------------------------------------
__global__ __launch_bounds__(512, 2) void gemm_i8_kernel(
    const signed char* __restrict__ qa,   // [M,K] int8
    const signed char* __restrict__ wb,   // [N,K] int8
    const float* __restrict__ scales,     // [M]
    const float* __restrict__ wscale,     // [N]
    const float* __restrict__ bias,       // [N]
    float* __restrict__ out)              // [M,N] f32
{
  __shared__ __align__(16) signed char As[2][2][256 * 64];  // 64 KiB
  __shared__ __align__(16) signed char Bs[2][2][256 * 64];  // 64 KiB

  const int tid = threadIdx.x;
  const int lane = tid & 63;
  const int wv = tid >> 6;       // 0..7
  const int wr = wv >> 2;        // 0..1 (M half)
  const int wc = wv & 3;         // 0..3 (N quarter)

  const int n0 = blockIdx.x * BN;
  const int m0 = blockIdx.y * BM;

  const signed char* Ag = qa + (size_t)m0 * KDIM;
  const signed char* Bg = wb + (size_t)n0 * KDIM;

  // stage one 16 KiB half-tile (256 rows x 64 B of K-half kh) for tile kt.
  // LDS dest linear (wave-uniform base + lane*16); swizzle via permuted
  // GLOBAL source chunk: c_g = c_lds ^ ((r>>1)&3).  2 loads per thread.
  auto stageH = [&](signed char* dst, const signed char* g, int kt, int kh) {
#pragma unroll
    for (int i = 0; i < 2; ++i) {
      const int chunk = i * 512 + tid;              // 0..1023
      const int r = chunk >> 2;                     // row 0..255
      const int cg = (chunk & 3) ^ ((r >> 1) & 3);  // swizzled global chunk
      gload_lds16(g + (size_t)r * KDIM + (size_t)kt * BK + kh * 64 + cg * 16,
                  dst + (i * 512 + wv * 64) * 16);
    }
  };

  // fragment reads: global chunk ksel of row r lives at LDS chunk
  // ksel ^ ((r>>1)&3); frag-row bases are multiples of 16 so the XOR term
  // is a per-lane constant.
  const int swz16 = (((lane >> 4) ^ (((lane & 15) >> 1) & 3)) << 4);
  const int frow_a = wr * 128 + (lane & 15);
  const int frow_b = wc * 64 + (lane & 15);

  auto ardA = [&](const signed char* plane, int mi) -> v4i {
    return *(const v4i*)(plane + (frow_a + mi * 16) * 64 + swz16);
  };
  auto ardB = [&](const signed char* plane, int ni) -> v4i {
    return *(const v4i*)(plane + (frow_b + ni * 16) * 64 + swz16);
  };

  v4i acc[8][4] = {};
  v4i af[4], af2[4], bfrag[4];

  // prologue: stage kh0(0), kh1(0), kh0(1)  (12 loads/thread)
  stageH(&As[0][0][0], Ag, 0, 0);
  stageH(&Bs[0][0][0], Bg, 0, 0);
  stageH(&As[0][1][0], Ag, 0, 1);
  stageH(&Bs[0][1][0], Bg, 0, 1);
  stageH(&As[1][0][0], Ag, 1, 0);
  stageH(&Bs[1][0][0], Bg, 1, 0);
  asm volatile("s_waitcnt vmcnt(8)" ::: "memory");  // kh0(0) A+B resident
  __builtin_amdgcn_s_barrier();

  for (int t = 0; t < NT; ++t) {
    const int cur = t & 1;
    const int nxt = cur ^ 1;
    const signed char* A0 = &As[cur][0][0];
    const signed char* A1 = &As[cur][1][0];
    const signed char* B0 = &Bs[cur][0][0];
    const signed char* B1 = &Bs[cur][1][0];

    // ================= phase A : K-slice kk0 =================
#pragma unroll
    for (int mi = 0; mi < 4; ++mi) af[mi] = ardA(A0, mi);
#pragma unroll
    for (int ni = 0; ni < 4; ++ni) bfrag[ni] = ardB(B0, ni);
    if (t + 1 < NT) {
      stageH(&As[nxt][1][0], Ag, t + 1, 1);   // slot freed @ phB(t-1) barrier
      stageH(&Bs[nxt][1][0], Bg, t + 1, 1);
    }
    __builtin_amdgcn_s_barrier();
    asm volatile("s_waitcnt lgkmcnt(0)" ::: "memory");
    __builtin_amdgcn_s_setprio(1);
#pragma unroll
    for (int mi = 0; mi < 4; ++mi)
#pragma unroll
      for (int ni = 0; ni < 4; ++ni)
        acc[mi][ni] = __builtin_amdgcn_mfma_i32_16x16x64_i8(
            af[mi], bfrag[ni], acc[mi][ni], 0, 0, 0);
    // quad-1 A reads: unfenced — compiler schedules them under the MFMAs
#pragma unroll
    for (int mi = 0; mi < 4; ++mi) af2[mi] = ardA(A0, mi + 4);
#pragma unroll
    for (int mi = 0; mi < 4; ++mi)
#pragma unroll
      for (int ni = 0; ni < 4; ++ni)
        acc[mi + 4][ni] = __builtin_amdgcn_mfma_i32_16x16x64_i8(
            af2[mi], bfrag[ni], acc[mi + 4][ni], 0, 0, 0);
    __builtin_amdgcn_s_setprio(0);
    // publish kh1(t) (staged @ phA(t-1)); keep 8 in flight
    if (t + 1 < NT) { asm volatile("s_waitcnt vmcnt(8)" ::: "memory"); }
    else            { asm volatile("s_waitcnt vmcnt(0)" ::: "memory"); }
    __builtin_amdgcn_s_barrier();

    // ================= phase B : K-slice kk1 =================
#pragma unroll
    for (int mi = 0; mi < 4; ++mi) af[mi] = ardA(A1, mi);
#pragma unroll
    for (int ni = 0; ni < 4; ++ni) bfrag[ni] = ardB(B1, ni);
    if (t + 2 < NT) {
      stageH(&As[cur][0][0], Ag, t + 2, 0);   // slot freed @ phA(t) barrier
      stageH(&Bs[cur][0][0], Bg, t + 2, 0);
    }
    __builtin_amdgcn_s_barrier();
    asm volatile("s_waitcnt lgkmcnt(0)" ::: "memory");
    __builtin_amdgcn_s_setprio(1);
#pragma unroll
    for (int mi = 0; mi < 4; ++mi)
#pragma unroll
      for (int ni = 0; ni < 4; ++ni)
        acc[mi][ni] = __builtin_amdgcn_mfma_i32_16x16x64_i8(
            af[mi], bfrag[ni], acc[mi][ni], 0, 0, 0);
#pragma unroll
    for (int mi = 0; mi < 4; ++mi) af2[mi] = ardA(A1, mi + 4);
#pragma unroll
    for (int mi = 0; mi < 4; ++mi)
#pragma unroll
      for (int ni = 0; ni < 4; ++ni)
        acc[mi + 4][ni] = __builtin_amdgcn_mfma_i32_16x16x64_i8(
            af2[mi], bfrag[ni], acc[mi + 4][ni], 0, 0, 0);
    __builtin_amdgcn_s_setprio(0);
    // publish kh0(t+1) (staged @ phB(t-1))
    if (t + 2 < NT)      { asm volatile("s_waitcnt vmcnt(8)" ::: "memory"); }
    else if (t + 1 < NT) { asm volatile("s_waitcnt vmcnt(4)" ::: "memory"); }
    __builtin_amdgcn_s_barrier();
  }

  // epilogue: dequant + bias, f32 store
  const int cl = lane & 15;
  const int rb = (lane >> 4) * 4;
#pragma unroll
  for (int ni = 0; ni < 4; ++ni) {
    const int n = n0 + wc * 64 + ni * 16 + cl;
    const float wsc = wscale[n];
    const float bs = bias[n];
#pragma unroll
    for (int mi = 0; mi < 8; ++mi) {
      const int mb = m0 + wr * 128 + mi * 16 + rb;
#pragma unroll
      for (int j = 0; j < 4; ++j) {
        const int m = mb + j;
        out[(size_t)m * NDIM + n] =
            (float)acc[mi][ni][j] * scales[m] * wsc + bs;
      }
    }
  }
}

// ---------------------------------------------------------------------------
extern "C" void kernel_launch(void* const* d_in, const int* in_sizes, int n_in,
                              void* d_out, int out_size, void* d_ws, size_t ws_size,
                              hipStream_t stream) {
  const float* x = (const float*)d_in[0];        // f32 [M,K] (fp16 upcast)
  const int* w32 = (const int*)d_in[1];          // int32 [N,K]
  const float* wscale = (const float*)d_in[2];   // [N]
  const float* bias = (const float*)d_in[3];     // [N]
  float* out = (float*)d_out;                    // f32 [M,N]

  float* scales = (float*)d_ws;                                  // 16 KB slot
  signed char* qbuf = (signed char*)d_ws + 16384;                // M*K int8
  signed char* wpack = (signed char*)d_ws + 16384 + (size_t)MDIM * KDIM;

  quant_kernel<<<MDIM, 256, 0, stream>>>(x, (unsigned*)qbuf, scales);

  const int n_units = (NDIM * KDIM) / 4;
  pack_kernel<<<2048, 256, 0, stream>>>((const int4*)w32, (unsigned*)wpack,
                                        n_units);

  dim3 grid(NDIM / BN, MDIM / BM);   // 43 x 16, row-major
  gemm_i8_kernel<<<grid, 512, 0, stream>>>(qbuf, wpack, scales, wscale, bias,
                                           out);
}

// Round 11
// 305.051 us; speedup vs baseline: 5.9978x; 1.0118x over previous
//
#include <hip/hip_runtime.h>
#include <hip/hip_bf16.h>

#define MDIM 4096
#define KDIM 4096
#define NDIM 11008

#define BM 256
#define BN 256
#define BK 128            // int8 per K-tile = four K=32 MFMA slices
#define NT (KDIM / BK)    // 32 K-tiles

typedef int v4i  __attribute__((ext_vector_type(4)));
typedef int v16i __attribute__((ext_vector_type(16)));

__device__ __forceinline__ void gload_lds16(const void* g, void* s) {
  __builtin_amdgcn_global_load_lds(
      (const __attribute__((address_space(1))) void*)g,
      (__attribute__((address_space(3))) void*)s, 16, 0, 0);
}

// ---------------------------------------------------------------------------
// Kernel 1: per-token dynamic int8 quant of f32 x -> q[M,K] int8, scale[M] f32
// ---------------------------------------------------------------------------
__global__ __launch_bounds__(256) void quant_kernel(
    const float* __restrict__ x,
    unsigned* __restrict__ q,
    float* __restrict__ scales)
{
  const int row = blockIdx.x;
  const int tid = threadIdx.x;
  const float4* xr = (const float4*)(x + (size_t)row * KDIM);
  float4 v[4];
#pragma unroll
  for (int i = 0; i < 4; ++i) v[i] = xr[tid + i * 256];

  float amax = 0.f;
#pragma unroll
  for (int i = 0; i < 4; ++i) {
    amax = fmaxf(amax, fmaxf(fmaxf(fabsf(v[i].x), fabsf(v[i].y)),
                             fmaxf(fabsf(v[i].z), fabsf(v[i].w))));
  }
#pragma unroll
  for (int off = 32; off >= 1; off >>= 1)
    amax = fmaxf(amax, __shfl_xor(amax, off));
  __shared__ float red[4];
  const int lane = tid & 63, wv = tid >> 6;
  if (lane == 0) red[wv] = amax;
  __syncthreads();
  amax = fmaxf(fmaxf(red[0], red[1]), fmaxf(red[2], red[3]));

  const float scale = fmaxf(amax, 1e-7f) * (1.0f / 127.0f);
  const float rs = 1.0f / scale;
  if (tid == 0) scales[row] = scale;

#pragma unroll
  for (int i = 0; i < 4; ++i) {
    float e[4] = {v[i].x, v[i].y, v[i].z, v[i].w};
    unsigned w = 0;
#pragma unroll
    for (int j = 0; j < 4; ++j) {
      float qf = rintf(e[j] * rs);
      qf = fminf(fmaxf(qf, -128.f), 127.f);
      int qi = (int)qf;
      w |= ((unsigned)(qi & 255)) << (8 * j);
    }
    q[(size_t)row * (KDIM / 4) + tid + i * 256] = w;
  }
}

// ---------------------------------------------------------------------------
// Kernel 2: pack int32 weight [N,K] -> int8 [N,K]
// ---------------------------------------------------------------------------
__global__ __launch_bounds__(256) void pack_kernel(
    const int4* __restrict__ w32, unsigned* __restrict__ w8, int n_units)
{
  int idx = blockIdx.x * 256 + threadIdx.x;
  const int stride = gridDim.x * 256;
  for (; idx < n_units; idx += stride) {
    int4 v = w32[idx];
    unsigned d = ((unsigned)(v.x & 255)) | ((unsigned)(v.y & 255) << 8) |
                 ((unsigned)(v.z & 255) << 16) | ((unsigned)(v.w & 255) << 24);
    w8[idx] = d;
  }
}

// ---------------------------------------------------------------------------
// Kernel 3: int8 GEMM, 256x256 tile, mfma_i32_32x32x32_i8, slice-pipelined.
// 512 threads = 8 waves (2M x 4N); per-wave output 128x64 = 4x2 32x32 tiles,
// acc[4][2] x v16i = 128 AGPR. Per K-tile: 4 slices of K=32; fragment regs
// double-banked (afA/afB, bfA/bfB) so reads of slice s+1 issue before the
// MFMAs of slice s — compiler's counted lgkmcnt hides reads under MFMA.
// ONE barrier per tile (vmcnt(0)+barrier at the boundary). Swizzle: 16B
// chunk c ^= ((row>>1)&3) both-sides (conflict-free for this read pattern:
// exactly 8 lanes per bank-group).
// ---------------------------------------------------------------------------
__global__ __launch_bounds__(512, 2) void gemm_i8_kernel(
    const signed char* __restrict__ qa,   // [M,K] int8
    const signed char* __restrict__ wb,   // [N,K] int8
    const float* __restrict__ scales,     // [M]
    const float* __restrict__ wscale,     // [N]
    const float* __restrict__ bias,       // [N]
    float* __restrict__ out)              // [M,N] f32
{
  __shared__ __align__(16) signed char As[2][2][256 * 64];  // 64 KiB
  __shared__ __align__(16) signed char Bs[2][2][256 * 64];  // 64 KiB

  const int tid = threadIdx.x;
  const int lane = tid & 63;
  const int wv = tid >> 6;       // 0..7
  const int wr = wv >> 2;        // 0..1 (M half)
  const int wc = wv & 3;         // 0..3 (N quarter)

  const int n0 = blockIdx.x * BN;
  const int m0 = blockIdx.y * BM;

  const signed char* Ag = qa + (size_t)m0 * KDIM;
  const signed char* Bg = wb + (size_t)n0 * KDIM;

  // stage one 16 KiB half-tile (256 rows x 64 B of K-half kh) for tile kt.
  // LDS dest linear; swizzle via permuted GLOBAL source chunk:
  // c_g = c_lds ^ ((r>>1)&3). 2 gloads per thread.
  auto stageH = [&](signed char* dst, const signed char* g, int kt, int kh) {
#pragma unroll
    for (int i = 0; i < 2; ++i) {
      const int chunk = i * 512 + tid;              // 0..1023
      const int r = chunk >> 2;                     // row 0..255
      const int cg = (chunk & 3) ^ ((r >> 1) & 3);  // swizzled global chunk
      gload_lds16(g + (size_t)r * KDIM + (size_t)kt * BK + kh * 64 + cg * 16,
                  dst + (i * 512 + wv * 64) * 16);
    }
  };

  // 32x32 fragment read: lane holds row (lane&31), 16 K-bytes at
  // k-half `half` (0/1 within the 64B kh plane), hi=(lane>>5) selects 16B.
  const int hi = lane >> 5;            // 0..1
  const int rl = lane & 31;            // row within 32x32 tile
  const int swz = (rl >> 1) & 3;       // per-lane swizzle term (bases %32==0)
  auto ard = [&](const signed char* plane, int rowbase, int half) -> v4i {
    const int chunk = ((half << 1) | hi) ^ swz;
    return *(const v4i*)(plane + (size_t)(rowbase + rl) * 64 + (chunk << 4));
  };

  v16i acc[4][2] = {};
  v4i afA[4], afB[4], bfA[2], bfB[2];

  // prologue: stage tile 0 fully
  stageH(&As[0][0][0], Ag, 0, 0);
  stageH(&Bs[0][0][0], Bg, 0, 0);
  stageH(&As[0][1][0], Ag, 0, 1);
  stageH(&Bs[0][1][0], Bg, 0, 1);
  asm volatile("s_waitcnt vmcnt(0)" ::: "memory");
  __builtin_amdgcn_s_barrier();

  const int arow0 = wr * 128;
  const int brow0 = wc * 64;

  for (int t = 0; t < NT; ++t) {
    const int cur = t & 1;
    const int nxt = cur ^ 1;
    const bool pf = (t + 1 < NT);
    const signed char* A0 = &As[cur][0][0];
    const signed char* A1 = &As[cur][1][0];
    const signed char* B0 = &Bs[cur][0][0];
    const signed char* B1 = &Bs[cur][1][0];

    // slice 0 reads (bank A): kh0, half0
#pragma unroll
    for (int mi = 0; mi < 4; ++mi) afA[mi] = ard(A0, arow0 + mi * 32, 0);
#pragma unroll
    for (int ni = 0; ni < 2; ++ni) bfA[ni] = ard(B0, brow0 + ni * 32, 0);
    if (pf) stageH(&As[nxt][0][0], Ag, t + 1, 0);

    // slice 1 reads (bank B): kh0, half1
#pragma unroll
    for (int mi = 0; mi < 4; ++mi) afB[mi] = ard(A0, arow0 + mi * 32, 1);
#pragma unroll
    for (int ni = 0; ni < 2; ++ni) bfB[ni] = ard(B0, brow0 + ni * 32, 1);
    if (pf) stageH(&Bs[nxt][0][0], Bg, t + 1, 0);

    // MFMA slice 0 (bank A) — auto lgkmcnt leaves slice-1 reads in flight
    __builtin_amdgcn_s_setprio(1);
#pragma unroll
    for (int mi = 0; mi < 4; ++mi)
#pragma unroll
      for (int ni = 0; ni < 2; ++ni)
        acc[mi][ni] = __builtin_amdgcn_mfma_i32_32x32x32_i8(
            afA[mi], bfA[ni], acc[mi][ni], 0, 0, 0);
    __builtin_amdgcn_s_setprio(0);

    // slice 2 reads (bank A): kh1, half0
#pragma unroll
    for (int mi = 0; mi < 4; ++mi) afA[mi] = ard(A1, arow0 + mi * 32, 0);
#pragma unroll
    for (int ni = 0; ni < 2; ++ni) bfA[ni] = ard(B1, brow0 + ni * 32, 0);
    if (pf) stageH(&As[nxt][1][0], Ag, t + 1, 1);

    // MFMA slice 1 (bank B)
    __builtin_amdgcn_s_setprio(1);
#pragma unroll
    for (int mi = 0; mi < 4; ++mi)
#pragma unroll
      for (int ni = 0; ni < 2; ++ni)
        acc[mi][ni] = __builtin_amdgcn_mfma_i32_32x32x32_i8(
            afB[mi], bfB[ni], acc[mi][ni], 0, 0, 0);
    __builtin_amdgcn_s_setprio(0);

    // slice 3 reads (bank B): kh1, half1
#pragma unroll
    for (int mi = 0; mi < 4; ++mi) afB[mi] = ard(A1, arow0 + mi * 32, 1);
#pragma unroll
    for (int ni = 0; ni < 2; ++ni) bfB[ni] = ard(B1, brow0 + ni * 32, 1);
    if (pf) stageH(&Bs[nxt][1][0], Bg, t + 1, 1);

    // MFMA slice 2 (bank A)
    __builtin_amdgcn_s_setprio(1);
#pragma unroll
    for (int mi = 0; mi < 4; ++mi)
#pragma unroll
      for (int ni = 0; ni < 2; ++ni)
        acc[mi][ni] = __builtin_amdgcn_mfma_i32_32x32x32_i8(
            afA[mi], bfA[ni], acc[mi][ni], 0, 0, 0);
    __builtin_amdgcn_s_setprio(0);

    // MFMA slice 3 (bank B)
    __builtin_amdgcn_s_setprio(1);
#pragma unroll
    for (int mi = 0; mi < 4; ++mi)
#pragma unroll
      for (int ni = 0; ni < 2; ++ni)
        acc[mi][ni] = __builtin_amdgcn_mfma_i32_32x32x32_i8(
            afB[mi], bfB[ni], acc[mi][ni], 0, 0, 0);
    __builtin_amdgcn_s_setprio(0);

    // tile boundary: next tile's 4 half-tiles must be resident
    asm volatile("s_waitcnt vmcnt(0)" ::: "memory");
    __builtin_amdgcn_s_barrier();
  }

  // epilogue: dequant + bias, f32 store.
  // 32x32 C/D: n = lane&31, m = (reg&3) + 8*(reg>>2) + 4*(lane>>5)
#pragma unroll
  for (int ni = 0; ni < 2; ++ni) {
    const int n = n0 + wc * 64 + ni * 32 + rl;
    const float wsc = wscale[n];
    const float bs = bias[n];
#pragma unroll
    for (int mi = 0; mi < 4; ++mi) {
      const int mbase = m0 + wr * 128 + mi * 32 + 4 * hi;
#pragma unroll
      for (int r = 0; r < 16; ++r) {
        const int m = mbase + (r & 3) + 8 * (r >> 2);
        out[(size_t)m * NDIM + n] =
            (float)acc[mi][ni][r] * scales[m] * wsc + bs;
      }
    }
  }
}

// ---------------------------------------------------------------------------
extern "C" void kernel_launch(void* const* d_in, const int* in_sizes, int n_in,
                              void* d_out, int out_size, void* d_ws, size_t ws_size,
                              hipStream_t stream) {
  const float* x = (const float*)d_in[0];        // f32 [M,K] (fp16 upcast)
  const int* w32 = (const int*)d_in[1];          // int32 [N,K]
  const float* wscale = (const float*)d_in[2];   // [N]
  const float* bias = (const float*)d_in[3];     // [N]
  float* out = (float*)d_out;                    // f32 [M,N]

  float* scales = (float*)d_ws;                                  // 16 KB slot
  signed char* qbuf = (signed char*)d_ws + 16384;                // M*K int8
  signed char* wpack = (signed char*)d_ws + 16384 + (size_t)MDIM * KDIM;

  quant_kernel<<<MDIM, 256, 0, stream>>>(x, (unsigned*)qbuf, scales);

  const int n_units = (NDIM * KDIM) / 4;
  pack_kernel<<<2048, 256, 0, stream>>>((const int4*)w32, (unsigned*)wpack,
                                        n_units);

  dim3 grid(NDIM / BN, MDIM / BM);   // 43 x 16
  gemm_i8_kernel<<<grid, 512, 0, stream>>>(qbuf, wpack, scales, wscale, bias,
                                           out);
}

// Round 12
// 279.980 us; speedup vs baseline: 6.5349x; 1.0895x over previous
//
#include <hip/hip_runtime.h>
#include <hip/hip_bf16.h>

#define MDIM 4096
#define KDIM 4096
#define NDIM 11008

#define BM 256
#define BN 256
#define BK 128            // int8 per K-tile (two K=64 MFMA slices)
#define NT (KDIM / BK)    // 32 K-tiles

typedef int v4i __attribute__((ext_vector_type(4)));

__device__ __forceinline__ void gload_lds16(const void* g, void* s) {
  __builtin_amdgcn_global_load_lds(
      (const __attribute__((address_space(1))) void*)g,
      (__attribute__((address_space(3))) void*)s, 16, 0, 0);
}

// ---------------------------------------------------------------------------
// Kernel 1: per-token dynamic int8 quant of f32 x -> q[M,K] int8, scale[M] f32
// ---------------------------------------------------------------------------
__global__ __launch_bounds__(256) void quant_kernel(
    const float* __restrict__ x,
    unsigned* __restrict__ q,
    float* __restrict__ scales)
{
  const int row = blockIdx.x;
  const int tid = threadIdx.x;
  const float4* xr = (const float4*)(x + (size_t)row * KDIM);
  float4 v[4];
#pragma unroll
  for (int i = 0; i < 4; ++i) v[i] = xr[tid + i * 256];

  float amax = 0.f;
#pragma unroll
  for (int i = 0; i < 4; ++i) {
    amax = fmaxf(amax, fmaxf(fmaxf(fabsf(v[i].x), fabsf(v[i].y)),
                             fmaxf(fabsf(v[i].z), fabsf(v[i].w))));
  }
#pragma unroll
  for (int off = 32; off >= 1; off >>= 1)
    amax = fmaxf(amax, __shfl_xor(amax, off));
  __shared__ float red[4];
  const int lane = tid & 63, wv = tid >> 6;
  if (lane == 0) red[wv] = amax;
  __syncthreads();
  amax = fmaxf(fmaxf(red[0], red[1]), fmaxf(red[2], red[3]));

  const float scale = fmaxf(amax, 1e-7f) * (1.0f / 127.0f);
  const float rs = 1.0f / scale;
  if (tid == 0) scales[row] = scale;

#pragma unroll
  for (int i = 0; i < 4; ++i) {
    float e[4] = {v[i].x, v[i].y, v[i].z, v[i].w};
    unsigned w = 0;
#pragma unroll
    for (int j = 0; j < 4; ++j) {
      float qf = rintf(e[j] * rs);
      qf = fminf(fmaxf(qf, -128.f), 127.f);
      int qi = (int)qf;
      w |= ((unsigned)(qi & 255)) << (8 * j);
    }
    q[(size_t)row * (KDIM / 4) + tid + i * 256] = w;
  }
}

// ---------------------------------------------------------------------------
// Kernel 2: pack int32 weight [N,K] -> int8 [N,K]
// ---------------------------------------------------------------------------
__global__ __launch_bounds__(256) void pack_kernel(
    const int4* __restrict__ w32, unsigned* __restrict__ w8, int n_units)
{
  int idx = blockIdx.x * 256 + threadIdx.x;
  const int stride = gridDim.x * 256;
  for (; idx < n_units; idx += stride) {
    int4 v = w32[idx];
    unsigned d = ((unsigned)(v.x & 255)) | ((unsigned)(v.y & 255) << 8) |
                 ((unsigned)(v.z & 255) << 16) | ((unsigned)(v.w & 255) << 24);
    w8[idx] = d;
  }
}

// ---------------------------------------------------------------------------
// Kernel 3: int8 GEMM, 256x256 tile, 1024 threads = 16 waves (4M x 4N),
// per-wave output 64x64 -> acc[4][4] v4i = 64 AGPR, ~116 regs/wave total
// -> 4 waves/SIMD (2x the TLP of the 8-wave variants r5-r11, which were all
// pinned at MfmaUtil ~29% regardless of schedule: pipes ran serially with
// only 2 waves/SIMD). Minimal schedule: reads/MFMAs unfenced within a tile
// (compiler lgkmcnt + cross-wave overlap), ONE vmcnt(0)+barrier per tile.
// Swizzle: chunk c ^= ((r>>1)&3) both-sides (16-row frag reads conflict-free,
// verified r6). mfma_i32_16x16x64_i8.
// ---------------------------------------------------------------------------
__global__ __launch_bounds__(1024, 4) void gemm_i8_kernel(
    const signed char* __restrict__ qa,   // [M,K] int8
    const signed char* __restrict__ wb,   // [N,K] int8
    const float* __restrict__ scales,     // [M]
    const float* __restrict__ wscale,     // [N]
    const float* __restrict__ bias,       // [N]
    float* __restrict__ out)              // [M,N] f32
{
  __shared__ __align__(16) signed char As[2][2][256 * 64];  // 64 KiB
  __shared__ __align__(16) signed char Bs[2][2][256 * 64];  // 64 KiB

  const int tid = threadIdx.x;
  const int lane = tid & 63;
  const int wv = tid >> 6;       // 0..15
  const int wr = wv >> 2;        // 0..3 (M quarter)
  const int wc = wv & 3;         // 0..3 (N quarter)

  const int n0 = blockIdx.x * BN;
  const int m0 = blockIdx.y * BM;

  const signed char* Ag = qa + (size_t)m0 * KDIM;
  const signed char* Bg = wb + (size_t)n0 * KDIM;

  // stage one 16 KiB half-tile (256 rows x 64 B of K-half kh) for tile kt.
  // 1024 threads -> ONE gload_lds per thread. LDS dest linear (wave-uniform
  // base wv*1024 + lane*16); swizzle via permuted GLOBAL source chunk:
  // c_g = c_lds ^ ((r>>1)&3).
  auto stageH = [&](signed char* dst, const signed char* g, int kt, int kh) {
    const int r = tid >> 2;                     // row 0..255
    const int cg = (tid & 3) ^ ((r >> 1) & 3);  // swizzled global chunk
    gload_lds16(g + (size_t)r * KDIM + (size_t)kt * BK + kh * 64 + cg * 16,
                dst + wv * 1024);
  };

  // fragment reads: global chunk ksel of row r lives at LDS chunk
  // ksel ^ ((r>>1)&3); frag-row bases are multiples of 16 so the XOR term
  // is a per-lane constant.
  const int swz16 = (((lane >> 4) ^ (((lane & 15) >> 1) & 3)) << 4);
  const int frow_a = wr * 64 + (lane & 15);
  const int frow_b = wc * 64 + (lane & 15);

  auto ardA = [&](const signed char* plane, int mi) -> v4i {
    return *(const v4i*)(plane + (frow_a + mi * 16) * 64 + swz16);
  };
  auto ardB = [&](const signed char* plane, int ni) -> v4i {
    return *(const v4i*)(plane + (frow_b + ni * 16) * 64 + swz16);
  };

  v4i acc[4][4] = {};
  v4i af[4], bf[4];

  // prologue: stage tile 0 fully (4 gloads/thread)
  stageH(&As[0][0][0], Ag, 0, 0);
  stageH(&Bs[0][0][0], Bg, 0, 0);
  stageH(&As[0][1][0], Ag, 0, 1);
  stageH(&Bs[0][1][0], Bg, 0, 1);
  asm volatile("s_waitcnt vmcnt(0)" ::: "memory");
  __builtin_amdgcn_s_barrier();

  for (int t = 0; t < NT; ++t) {
    const int cur = t & 1;
    const int nxt = cur ^ 1;
    const bool pf = (t + 1 < NT);
    const signed char* A0 = &As[cur][0][0];
    const signed char* A1 = &As[cur][1][0];
    const signed char* B0 = &Bs[cur][0][0];
    const signed char* B1 = &Bs[cur][1][0];

    // ----- slice 0 (kh0): reads + stage, then MFMA (unfenced) -----
#pragma unroll
    for (int mi = 0; mi < 4; ++mi) af[mi] = ardA(A0, mi);
#pragma unroll
    for (int ni = 0; ni < 4; ++ni) bf[ni] = ardB(B0, ni);
    if (pf) {
      stageH(&As[nxt][0][0], Ag, t + 1, 0);
      stageH(&Bs[nxt][0][0], Bg, t + 1, 0);
    }
    __builtin_amdgcn_s_setprio(1);
#pragma unroll
    for (int mi = 0; mi < 4; ++mi)
#pragma unroll
      for (int ni = 0; ni < 4; ++ni)
        acc[mi][ni] = __builtin_amdgcn_mfma_i32_16x16x64_i8(
            af[mi], bf[ni], acc[mi][ni], 0, 0, 0);
    __builtin_amdgcn_s_setprio(0);

    // ----- slice 1 (kh1): reads + stage, then MFMA (unfenced) -----
#pragma unroll
    for (int mi = 0; mi < 4; ++mi) af[mi] = ardA(A1, mi);
#pragma unroll
    for (int ni = 0; ni < 4; ++ni) bf[ni] = ardB(B1, ni);
    if (pf) {
      stageH(&As[nxt][1][0], Ag, t + 1, 1);
      stageH(&Bs[nxt][1][0], Bg, t + 1, 1);
    }
    __builtin_amdgcn_s_setprio(1);
#pragma unroll
    for (int mi = 0; mi < 4; ++mi)
#pragma unroll
      for (int ni = 0; ni < 4; ++ni)
        acc[mi][ni] = __builtin_amdgcn_mfma_i32_16x16x64_i8(
            af[mi], bf[ni], acc[mi][ni], 0, 0, 0);
    __builtin_amdgcn_s_setprio(0);

    // tile boundary: publish next tile, free cur for staging at t+1
    asm volatile("s_waitcnt vmcnt(0)" ::: "memory");
    __builtin_amdgcn_s_barrier();
  }

  // epilogue: dequant + bias, f32 store (16x16 C/D: col=lane&15,
  // row=(lane>>4)*4+j — verified mapping)
  const int cl = lane & 15;
  const int rb = (lane >> 4) * 4;
#pragma unroll
  for (int ni = 0; ni < 4; ++ni) {
    const int n = n0 + wc * 64 + ni * 16 + cl;
    const float wsc = wscale[n];
    const float bs = bias[n];
#pragma unroll
    for (int mi = 0; mi < 4; ++mi) {
      const int mb = m0 + wr * 64 + mi * 16 + rb;
#pragma unroll
      for (int j = 0; j < 4; ++j) {
        const int m = mb + j;
        out[(size_t)m * NDIM + n] =
            (float)acc[mi][ni][j] * scales[m] * wsc + bs;
      }
    }
  }
}

// ---------------------------------------------------------------------------
extern "C" void kernel_launch(void* const* d_in, const int* in_sizes, int n_in,
                              void* d_out, int out_size, void* d_ws, size_t ws_size,
                              hipStream_t stream) {
  const float* x = (const float*)d_in[0];        // f32 [M,K] (fp16 upcast)
  const int* w32 = (const int*)d_in[1];          // int32 [N,K]
  const float* wscale = (const float*)d_in[2];   // [N]
  const float* bias = (const float*)d_in[3];     // [N]
  float* out = (float*)d_out;                    // f32 [M,N]

  float* scales = (float*)d_ws;                                  // 16 KB slot
  signed char* qbuf = (signed char*)d_ws + 16384;                // M*K int8
  signed char* wpack = (signed char*)d_ws + 16384 + (size_t)MDIM * KDIM;

  quant_kernel<<<MDIM, 256, 0, stream>>>(x, (unsigned*)qbuf, scales);

  const int n_units = (NDIM * KDIM) / 4;
  pack_kernel<<<2048, 256, 0, stream>>>((const int4*)w32, (unsigned*)wpack,
                                        n_units);

  dim3 grid(NDIM / BN, MDIM / BM);   // 43 x 16
  gemm_i8_kernel<<<grid, 1024, 0, stream>>>(qbuf, wpack, scales, wscale, bias,
                                            out);
}

// Round 13
// 270.541 us; speedup vs baseline: 6.7629x; 1.0349x over previous
//
#include <hip/hip_runtime.h>
#include <hip/hip_bf16.h>

#define MDIM 4096
#define KDIM 4096
#define NDIM 11008

#define BM 256
#define BN 256
#define BK 128            // int8 per K-tile (two K=64 MFMA slices)
#define NT (KDIM / BK)    // 32 K-tiles

typedef int v4i __attribute__((ext_vector_type(4)));

__device__ __forceinline__ void gload_lds16(const void* g, void* s) {
  __builtin_amdgcn_global_load_lds(
      (const __attribute__((address_space(1))) void*)g,
      (__attribute__((address_space(3))) void*)s, 16, 0, 0);
}

// ---------------------------------------------------------------------------
// Kernel 1: per-token dynamic int8 quant of f32 x -> q[M,K] int8, scale[M] f32
// ---------------------------------------------------------------------------
__global__ __launch_bounds__(256) void quant_kernel(
    const float* __restrict__ x,
    unsigned* __restrict__ q,
    float* __restrict__ scales)
{
  const int row = blockIdx.x;
  const int tid = threadIdx.x;
  const float4* xr = (const float4*)(x + (size_t)row * KDIM);
  float4 v[4];
#pragma unroll
  for (int i = 0; i < 4; ++i) v[i] = xr[tid + i * 256];

  float amax = 0.f;
#pragma unroll
  for (int i = 0; i < 4; ++i) {
    amax = fmaxf(amax, fmaxf(fmaxf(fabsf(v[i].x), fabsf(v[i].y)),
                             fmaxf(fabsf(v[i].z), fabsf(v[i].w))));
  }
#pragma unroll
  for (int off = 32; off >= 1; off >>= 1)
    amax = fmaxf(amax, __shfl_xor(amax, off));
  __shared__ float red[4];
  const int lane = tid & 63, wv = tid >> 6;
  if (lane == 0) red[wv] = amax;
  __syncthreads();
  amax = fmaxf(fmaxf(red[0], red[1]), fmaxf(red[2], red[3]));

  const float scale = fmaxf(amax, 1e-7f) * (1.0f / 127.0f);
  const float rs = 1.0f / scale;
  if (tid == 0) scales[row] = scale;

#pragma unroll
  for (int i = 0; i < 4; ++i) {
    float e[4] = {v[i].x, v[i].y, v[i].z, v[i].w};
    unsigned w = 0;
#pragma unroll
    for (int j = 0; j < 4; ++j) {
      float qf = rintf(e[j] * rs);
      qf = fminf(fmaxf(qf, -128.f), 127.f);
      int qi = (int)qf;
      w |= ((unsigned)(qi & 255)) << (8 * j);
    }
    q[(size_t)row * (KDIM / 4) + tid + i * 256] = w;
  }
}

// ---------------------------------------------------------------------------
// Kernel 2: pack int32 weight [N,K] -> int8 [N,K]
// ---------------------------------------------------------------------------
__global__ __launch_bounds__(256) void pack_kernel(
    const int4* __restrict__ w32, unsigned* __restrict__ w8, int n_units)
{
  int idx = blockIdx.x * 256 + threadIdx.x;
  const int stride = gridDim.x * 256;
  for (; idx < n_units; idx += stride) {
    int4 v = w32[idx];
    unsigned d = ((unsigned)(v.x & 255)) | ((unsigned)(v.y & 255) << 8) |
                 ((unsigned)(v.z & 255) << 16) | ((unsigned)(v.w & 255) << 24);
    w8[idx] = d;
  }
}

// ---------------------------------------------------------------------------
// Kernel 3: int8 GEMM, 256x256 tile, 1024 threads = 16 waves (4M x 4N),
// per-wave 64x64, acc[4][4] v4i = 64 AGPR; 64 arch VGPR -> exactly 128
// regs/wave = 4 waves/SIMD (register wall; launch_bounds pins it).
// NEW vs r12: counted-vmcnt 2-phase tile. Phase A: slice-0 reads, stage
// kh0(t+1), vmcnt(2)+barrier (publishes kh1(t), keeps 2 in flight),
// MFMA slice 0. Phase B: slice-1 reads (overlap MFMA0 issue), stage
// kh1(t+1), MFMA slice 1, vmcnt(2)+barrier (publishes kh0(t+1)).
// vmcnt never drains to 0 in steady state (m218 lever); every staged
// half-tile has >=1500 cyc of latency cover. Swizzle: chunk c ^= ((r>>1)&3)
// both-sides, 16-row fragment reads (measured 0 conflicts, r6/r12).
// ---------------------------------------------------------------------------
__global__ __launch_bounds__(1024, 4) void gemm_i8_kernel(
    const signed char* __restrict__ qa,   // [M,K] int8
    const signed char* __restrict__ wb,   // [N,K] int8
    const float* __restrict__ scales,     // [M]
    const float* __restrict__ wscale,     // [N]
    const float* __restrict__ bias,       // [N]
    float* __restrict__ out)              // [M,N] f32
{
  __shared__ __align__(16) signed char As[2][2][256 * 64];  // 64 KiB
  __shared__ __align__(16) signed char Bs[2][2][256 * 64];  // 64 KiB

  const int tid = threadIdx.x;
  const int lane = tid & 63;
  const int wv = tid >> 6;       // 0..15
  const int wr = wv >> 2;        // 0..3 (M quarter)
  const int wc = wv & 3;         // 0..3 (N quarter)

  const int n0 = blockIdx.x * BN;
  const int m0 = blockIdx.y * BM;

  const signed char* Ag = qa + (size_t)m0 * KDIM;
  const signed char* Bg = wb + (size_t)n0 * KDIM;

  // stage one 16 KiB half-tile (256 rows x 64 B of K-half kh) for tile kt.
  // 1024 threads -> ONE gload_lds per thread. LDS dest linear; swizzle via
  // permuted GLOBAL source chunk: c_g = c_lds ^ ((r>>1)&3).
  auto stageH = [&](signed char* dst, const signed char* g, int kt, int kh) {
    const int r = tid >> 2;                     // row 0..255
    const int cg = (tid & 3) ^ ((r >> 1) & 3);  // swizzled global chunk
    gload_lds16(g + (size_t)r * KDIM + (size_t)kt * BK + kh * 64 + cg * 16,
                dst + wv * 1024);
  };

  // fragment reads (16-row pattern, measured conflict-free)
  const int swz16 = (((lane >> 4) ^ (((lane & 15) >> 1) & 3)) << 4);
  const int frow_a = wr * 64 + (lane & 15);
  const int frow_b = wc * 64 + (lane & 15);

  auto ardA = [&](const signed char* plane, int mi) -> v4i {
    return *(const v4i*)(plane + (frow_a + mi * 16) * 64 + swz16);
  };
  auto ardB = [&](const signed char* plane, int ni) -> v4i {
    return *(const v4i*)(plane + (frow_b + ni * 16) * 64 + swz16);
  };

  v4i acc[4][4] = {};
  v4i af[4], bf[4];

  // prologue: stage tile 0 (kh0 then kh1); publish kh0, keep kh1 in flight
  stageH(&As[0][0][0], Ag, 0, 0);
  stageH(&Bs[0][0][0], Bg, 0, 0);
  stageH(&As[0][1][0], Ag, 0, 1);
  stageH(&Bs[0][1][0], Bg, 0, 1);
  asm volatile("s_waitcnt vmcnt(2)" ::: "memory");
  __builtin_amdgcn_s_barrier();

  for (int t = 0; t < NT; ++t) {
    const int cur = t & 1;
    const int nxt = cur ^ 1;
    const bool pf = (t + 1 < NT);
    const signed char* A0 = &As[cur][0][0];
    const signed char* A1 = &As[cur][1][0];
    const signed char* B0 = &Bs[cur][0][0];
    const signed char* B1 = &Bs[cur][1][0];

    // ----- phase A: slice 0 (kh0) -----
#pragma unroll
    for (int mi = 0; mi < 4; ++mi) af[mi] = ardA(A0, mi);
#pragma unroll
    for (int ni = 0; ni < 4; ++ni) bf[ni] = ardB(B0, ni);
    if (pf) {
      stageH(&As[nxt][0][0], Ag, t + 1, 0);
      stageH(&Bs[nxt][0][0], Bg, t + 1, 0);
    }
    // publish kh1(t): FIFO = {kh1(t) x2, kh0(t+1) x2} -> wait to 2
    if (pf) { asm volatile("s_waitcnt vmcnt(2)" ::: "memory"); }
    else    { asm volatile("s_waitcnt vmcnt(0)" ::: "memory"); }
    __builtin_amdgcn_s_barrier();
    __builtin_amdgcn_s_setprio(1);
#pragma unroll
    for (int mi = 0; mi < 4; ++mi)
#pragma unroll
      for (int ni = 0; ni < 4; ++ni)
        acc[mi][ni] = __builtin_amdgcn_mfma_i32_16x16x64_i8(
            af[mi], bf[ni], acc[mi][ni], 0, 0, 0);
    __builtin_amdgcn_s_setprio(0);

    // ----- phase B: slice 1 (kh1) — reads overlap slice-0 MFMA drain -----
#pragma unroll
    for (int mi = 0; mi < 4; ++mi) af[mi] = ardA(A1, mi);
#pragma unroll
    for (int ni = 0; ni < 4; ++ni) bf[ni] = ardB(B1, ni);
    if (pf) {
      stageH(&As[nxt][1][0], Ag, t + 1, 1);
      stageH(&Bs[nxt][1][0], Bg, t + 1, 1);
    }
    __builtin_amdgcn_s_setprio(1);
#pragma unroll
    for (int mi = 0; mi < 4; ++mi)
#pragma unroll
      for (int ni = 0; ni < 4; ++ni)
        acc[mi][ni] = __builtin_amdgcn_mfma_i32_16x16x64_i8(
            af[mi], bf[ni], acc[mi][ni], 0, 0, 0);
    __builtin_amdgcn_s_setprio(0);
    // publish kh0(t+1): FIFO = {kh0(t+1) x2, kh1(t+1) x2} -> wait to 2
    if (pf) { asm volatile("s_waitcnt vmcnt(2)" ::: "memory"); }
    else    { asm volatile("s_waitcnt vmcnt(0)" ::: "memory"); }
    __builtin_amdgcn_s_barrier();
  }

  // epilogue: dequant + bias, f32 store (16x16 C/D: col=lane&15,
  // row=(lane>>4)*4+j — verified mapping)
  const int cl = lane & 15;
  const int rb = (lane >> 4) * 4;
#pragma unroll
  for (int ni = 0; ni < 4; ++ni) {
    const int n = n0 + wc * 64 + ni * 16 + cl;
    const float wsc = wscale[n];
    const float bs = bias[n];
#pragma unroll
    for (int mi = 0; mi < 4; ++mi) {
      const int mb = m0 + wr * 64 + mi * 16 + rb;
#pragma unroll
      for (int j = 0; j < 4; ++j) {
        const int m = mb + j;
        out[(size_t)m * NDIM + n] =
            (float)acc[mi][ni][j] * scales[m] * wsc + bs;
      }
    }
  }
}

// ---------------------------------------------------------------------------
extern "C" void kernel_launch(void* const* d_in, const int* in_sizes, int n_in,
                              void* d_out, int out_size, void* d_ws, size_t ws_size,
                              hipStream_t stream) {
  const float* x = (const float*)d_in[0];        // f32 [M,K] (fp16 upcast)
  const int* w32 = (const int*)d_in[1];          // int32 [N,K]
  const float* wscale = (const float*)d_in[2];   // [N]
  const float* bias = (const float*)d_in[3];     // [N]
  float* out = (float*)d_out;                    // f32 [M,N]

  float* scales = (float*)d_ws;                                  // 16 KB slot
  signed char* qbuf = (signed char*)d_ws + 16384;                // M*K int8
  signed char* wpack = (signed char*)d_ws + 16384 + (size_t)MDIM * KDIM;

  quant_kernel<<<MDIM, 256, 0, stream>>>(x, (unsigned*)qbuf, scales);

  const int n_units = (NDIM * KDIM) / 4;
  pack_kernel<<<2048, 256, 0, stream>>>((const int4*)w32, (unsigned*)wpack,
                                        n_units);

  dim3 grid(NDIM / BN, MDIM / BM);   // 43 x 16
  gemm_i8_kernel<<<grid, 1024, 0, stream>>>(qbuf, wpack, scales, wscale, bias,
                                            out);
}